// Round 12
// baseline (103.594 us; speedup 1.0000x reference)
//
#include <hip/hip_runtime.h>
#include <hip/hip_bf16.h>

#define I_DIM 4096
#define J_DIM 4096
#define NPERM0 10
#define NPERM1 10
#define RROWS 4            // rows per K1 tile
#define CHUNKS 8           // column chunks == XCD count
#define CCOLS (J_DIM / CHUNKS)   // 512 cols per chunk (4 MiB bf16 slice)
#define K2_ROWS 16         // out rows per K2 block (4 waves x 4 rows)

typedef float          f32x4 __attribute__((ext_vector_type(4)));
typedef int            i32x4 __attribute__((ext_vector_type(4)));
typedef unsigned short u16x4 __attribute__((ext_vector_type(4)));
typedef unsigned short u16x8 __attribute__((ext_vector_type(8)));

// XOR-swizzle for 8-byte LDS slots: physical = s ^ ((s>>4)&7). Bijective.
// Transpose writes (s = 8*c8+k, fixed k): 16 consecutive lanes hit 16
// distinct low-4 slots -> all 32 banks exactly 4x per wave (b64 optimum).
__device__ __forceinline__ int swzB(int s) { return s ^ ((s >> 4) & 7); }

__device__ __forceinline__ float bf2f(unsigned short u) {
    return __uint_as_float((unsigned)u << 16);
}
__device__ __forceinline__ unsigned short f2bf(float f) {
    unsigned u = __float_as_uint(f);
    u += 0x7FFFu + ((u >> 16) & 1u);
    return (unsigned short)(u >> 16);
}

// soft mask: clip((xi-gamma)*sigmoid(x)+gamma, 0, 1), xi=1.1, gamma=-0.1
__device__ __forceinline__ float soft_mask(float x) {
    float s = 1.0f / (1.0f + __expf(-x));
    return fminf(fmaxf(1.2f * s - 0.1f, 0.0f), 1.0f);
}

// Issue NT loads for 2 rows of w,m (8 f32x4 = 32 VGPRs in flight).
__device__ __forceinline__ void issue_loads_2rows(
    const float* __restrict__ w, const float* __restrict__ m,
    int i, int c8, f32x4 pw[2][2], f32x4 pm[2][2]) {
#pragma unroll
    for (int r = 0; r < 2; ++r) {
        const f32x4* w4 = reinterpret_cast<const f32x4*>(
                              w + (size_t)(i + r) * J_DIM) + 2 * c8;
        const f32x4* m4 = reinterpret_cast<const f32x4*>(
                              m + (size_t)(i + r) * J_DIM) + 2 * c8;
        pw[r][0] = __builtin_nontemporal_load(w4);
        pw[r][1] = __builtin_nontemporal_load(w4 + 1);
        pm[r][0] = __builtin_nontemporal_load(m4);
        pm[r][1] = __builtin_nontemporal_load(m4 + 1);
    }
}

__device__ __forceinline__ u16x8 conv_row(f32x4 w0, f32x4 w1, f32x4 m0, f32x4 m1) {
    u16x8 o;
#pragma unroll
    for (int k = 0; k < 4; ++k) {
        o[k]     = f2bf(w0[k] * soft_mask(m0[k]));
        o[k + 4] = f2bf(w1[k] * soft_mask(m1[k]));
    }
    return o;
}

__device__ __forceinline__ void transpose_to_lds(u16x4* vlds, const u16x8 rowv[RROWS], int c8) {
#pragma unroll
    for (int k = 0; k < 8; ++k) {
        u16x4 t;
#pragma unroll
        for (int r = 0; r < RROWS; ++r) t[r] = rowv[r][k];
        vlds[swzB(8 * c8 + k)] = t;
    }
}

// One 4-column half of the col-mix gather. HALF is a template param so all
// o[] indexing is compile-time static (rule #20: no scratch).
template<int HALF>
__device__ __forceinline__ void gather_half(
    float (&o)[RROWS][8], const u16x4* vlds,
    const int* __restrict__ perm1, const float* __restrict__ ps1, int c8) {
    const int off = 2 * c8 + HALF;
#pragma unroll 2
    for (int q = 0; q < NPERM1; ++q) {
        i32x4 pc = reinterpret_cast<const i32x4*>(perm1 + (size_t)q * J_DIM)[off];
        f32x4 s  = reinterpret_cast<const f32x4*>(ps1  + (size_t)q * J_DIM)[off];
        u16x4 g[4];
#pragma unroll
        for (int k = 0; k < 4; ++k) g[k] = vlds[swzB(pc[k])];
#pragma unroll
        for (int k = 0; k < 4; ++k)
#pragma unroll
            for (int r = 0; r < RROWS; ++r)
                o[r][HALF * 4 + k] += s[k] * bf2f(g[k][r]);
    }
}

__device__ __forceinline__ void store_u(
    unsigned short* __restrict__ ub, int i, int c8, const float (&o)[RROWS][8]) {
#pragma unroll
    for (int r = 0; r < RROWS; ++r) {
        u16x8 ob;
#pragma unroll
        for (int k = 0; k < 8; ++k) ob[k] = f2bf(o[r][k]);
        *reinterpret_cast<u16x8*>(ub + (size_t)(i + r) * J_DIM + (size_t)c8 * 8) = ob;
    }
}

// K1: fused soft-mask + column-mix, software-pipelined over 2 tiles/block.
//   u[i,c] = sum_q ps1[q,c] * sw[i, perm1[q,c]]
// Grid = 512 blocks, each handles row-tiles bid and bid+512. Tile B's w/m
// loads are issued before/between tile A's gather halves so HBM streaming
// hides under the LDS gather (round-11: phases ran serialized, 50 us).
// Hand-unrolled 2-tile pipeline, no conditional tails (round-8 spill lesson).
__global__ __launch_bounds__(512, 4) void maskcolmix_kernel(
    const float* __restrict__ w,              // (I, J) f32
    const float* __restrict__ m,              // (I, J) f32
    const float* __restrict__ ps1,            // (NPERM1, J)
    const int*   __restrict__ perm1,          // (NPERM1, J)
    unsigned short* __restrict__ ub) {        // (I, J) bf16 out
    __shared__ u16x4 vlds[J_DIM];             // 32 KiB

    const int c8 = threadIdx.x;               // column octet, 0..511
    const int i0 = blockIdx.x * RROWS;                    // tile A
    const int i1 = (blockIdx.x + (int)gridDim.x) * RROWS; // tile B

    // ---- tile A: load + convert + stage ----
    u16x8 rowv[RROWS];
    {
        f32x4 aw[2][2], am[2][2], bw[2][2], bm[2][2];
        issue_loads_2rows(w, m, i0,     c8, aw, am);
        issue_loads_2rows(w, m, i0 + 2, c8, bw, bm);
        rowv[0] = conv_row(aw[0][0], aw[0][1], am[0][0], am[0][1]);
        rowv[1] = conv_row(aw[1][0], aw[1][1], am[1][0], am[1][1]);
        rowv[2] = conv_row(bw[0][0], bw[0][1], bm[0][0], bm[0][1]);
        rowv[3] = conv_row(bw[1][0], bw[1][1], bm[1][0], bm[1][1]);
    }
    transpose_to_lds(vlds, rowv, c8);
    __syncthreads();

    float o[RROWS][8];
#pragma unroll
    for (int r = 0; r < RROWS; ++r)
#pragma unroll
        for (int k = 0; k < 8; ++k) o[r][k] = 0.f;

    // ---- gather A, prefetching tile B in 2-row chunks between halves ----
    f32x4 pw[2][2], pm[2][2];
    issue_loads_2rows(w, m, i1, c8, pw, pm);       // in flight during half 0
    gather_half<0>(o, vlds, perm1, ps1, c8);
    rowv[0] = conv_row(pw[0][0], pw[0][1], pm[0][0], pm[0][1]);
    rowv[1] = conv_row(pw[1][0], pw[1][1], pm[1][0], pm[1][1]);
    issue_loads_2rows(w, m, i1 + 2, c8, pw, pm);   // in flight during half 1
    gather_half<1>(o, vlds, perm1, ps1, c8);
    rowv[2] = conv_row(pw[0][0], pw[0][1], pm[0][0], pm[0][1]);
    rowv[3] = conv_row(pw[1][0], pw[1][1], pm[1][0], pm[1][1]);
    store_u(ub, i0, c8, o);

    __syncthreads();                               // gathers of A all done
    transpose_to_lds(vlds, rowv, c8);
    __syncthreads();

    // ---- gather B (no prefetch) ----
#pragma unroll
    for (int r = 0; r < RROWS; ++r)
#pragma unroll
        for (int k = 0; k < 8; ++k) o[r][k] = 0.f;
    gather_half<0>(o, vlds, perm1, ps1, c8);
    gather_half<1>(o, vlds, perm1, ps1, c8);
    store_u(ub, i1, c8, o);
}

// K2: row-mix on u -> final out (f32):
//   out[i,c] = sum_p ps0[p,i] * u[perm0[p,i], c]
// Column-chunked (chunk = bid % 8 -> XCD): each XCD gathers from a 4 MiB
// u slice resident in its L2. NT out stores keep that slice unevicted.
// launch_bounds(256,8): 8 blocks/CU = 32 waves (round-11 ran at 16) to
// hide the L2-gather latency; loop shape fits 64 VGPRs (round-6 proven).
__global__ __launch_bounds__(256, 8) void rowmix_out_kernel(
    const unsigned short* __restrict__ ub,    // (I, J) bf16
    const float* __restrict__ ps0,            // (NPERM0, I)
    const int*   __restrict__ perm0,          // (NPERM0, I)
    float* __restrict__ out) {                // (I, J) f32
    const int chunk = blockIdx.x & (CHUNKS - 1);
    const int rg    = blockIdx.x / CHUNKS;
    const int wave  = threadIdx.x >> 6;
    const int lane  = threadIdx.x & 63;
    const int i0    = rg * K2_ROWS + wave * 4;           // 4 rows per wave
    const size_t colbase = (size_t)chunk * CCOLS + (size_t)lane * 8;

    float acc[4][8];
#pragma unroll
    for (int r = 0; r < 4; ++r)
#pragma unroll
        for (int k = 0; k < 8; ++k) acc[r][k] = 0.f;

#pragma unroll 2
    for (int p = 0; p < NPERM0; ++p) {
        u16x8 vv[4];
#pragma unroll
        for (int r = 0; r < 4; ++r) {
            int row = perm0[p * I_DIM + i0 + r];          // wave-uniform
            vv[r] = *reinterpret_cast<const u16x8*>(
                        ub + (size_t)row * J_DIM + colbase);
        }
#pragma unroll
        for (int r = 0; r < 4; ++r) {
            float s = ps0[p * I_DIM + i0 + r];            // wave-uniform
#pragma unroll
            for (int k = 0; k < 8; ++k) acc[r][k] += s * bf2f(vv[r][k]);
        }
    }
#pragma unroll
    for (int r = 0; r < 4; ++r) {
        f32x4 t0, t1;
#pragma unroll
        for (int k = 0; k < 4; ++k) { t0[k] = acc[r][k]; t1[k] = acc[r][k + 4]; }
        float* dst = out + (size_t)(i0 + r) * J_DIM + colbase;
        __builtin_nontemporal_store(t0, reinterpret_cast<f32x4*>(dst));
        __builtin_nontemporal_store(t1, reinterpret_cast<f32x4*>(dst) + 1);
    }
}

extern "C" void kernel_launch(void* const* d_in, const int* in_sizes, int n_in,
                              void* d_out, int out_size, void* d_ws, size_t ws_size,
                              hipStream_t stream) {
    const float* weight = (const float*)d_in[0];
    const float* smask  = (const float*)d_in[1];
    const float* ps0    = (const float*)d_in[2];
    const float* ps1    = (const float*)d_in[3];
    const int*   perm0  = (const int*)d_in[4];
    const int*   perm1  = (const int*)d_in[5];
    float* out = (float*)d_out;

    unsigned short* ub = (unsigned short*)d_ws;   // 32 MiB intermediate u

    maskcolmix_kernel<<<I_DIM / RROWS / 2, 512, 0, stream>>>(
        weight, smask, ps1, perm1, ub);
    rowmix_out_kernel<<<CHUNKS * (I_DIM / K2_ROWS), 256, 0, stream>>>(
        ub, ps0, perm0, out);
}

// Round 13
// 92.354 us; speedup vs baseline: 1.1217x; 1.1217x over previous
//
#include <hip/hip_runtime.h>
#include <hip/hip_bf16.h>

#define I_DIM 4096
#define J_DIM 4096
#define NPERM0 10
#define NPERM1 10
#define RROWS 4            // rows per K1 block
#define CHUNKS 8           // column chunks == XCD count
#define CCOLS (J_DIM / CHUNKS)   // 512 cols per chunk (4 MiB bf16 slice)
#define K2_ROWS 16         // out rows per K2 block (4 waves x 4 rows)

typedef float          f32x4 __attribute__((ext_vector_type(4)));
typedef int            i32x4 __attribute__((ext_vector_type(4)));
typedef unsigned short u16x4 __attribute__((ext_vector_type(4)));
typedef unsigned short u16x8 __attribute__((ext_vector_type(8)));

// XOR-swizzle for 8-byte LDS slots: physical = s ^ ((s>>4)&7). Bijective.
// Transpose writes (s = 8*c8+k, fixed k): 16 consecutive lanes hit 16
// distinct low-4 slots -> all 32 banks exactly 4x per wave (b64 optimum).
__device__ __forceinline__ int swzB(int s) { return s ^ ((s >> 4) & 7); }

__device__ __forceinline__ float bf2f(unsigned short u) {
    return __uint_as_float((unsigned)u << 16);
}
__device__ __forceinline__ unsigned short f2bf(float f) {
    unsigned u = __float_as_uint(f);
    u += 0x7FFFu + ((u >> 16) & 1u);
    return (unsigned short)(u >> 16);
}

// soft mask: clip((xi-gamma)*sigmoid(x)+gamma, 0, 1), xi=1.1, gamma=-0.1
__device__ __forceinline__ float soft_mask(float x) {
    float s = 1.0f / (1.0f + __expf(-x));
    return fminf(fmaxf(1.2f * s - 0.1f, 0.0f), 1.0f);
}

// K1: fused soft-mask + column-mix (round-11 proven body):
//   u[i,c] = sum_q ps1[q,c] * sw[i, perm1[q,c]],  sw[i,j] = w[i,j]*mask(m[i,j])
// launch_bounds(512,8): 8 waves/SIMD -> 4 blocks/CU (round 11 ran at 2:
// for 512-thread blocks arg=4 means only 16 waves/CU). Resident blocks sit
// in different phases (stream vs gather) -> natural overlap, no manual
// pipelining (round-12 lesson: manual 2-tile pipeline regressed).
// K1 body used 40 VGPRs in round 11 -> fits the 64-VGPR cap without spill.
__global__ __launch_bounds__(512, 8) void maskcolmix_kernel(
    const float* __restrict__ w,              // (I, J) f32
    const float* __restrict__ m,              // (I, J) f32
    const float* __restrict__ ps1,            // (NPERM1, J)
    const int*   __restrict__ perm1,          // (NPERM1, J)
    unsigned short* __restrict__ ub) {        // (I, J) bf16 out
    __shared__ u16x4 vlds[J_DIM];             // 32 KiB

    const int i0 = blockIdx.x * RROWS;
    const int c8 = threadIdx.x;               // column octet, 0..511

    // Load w,m (8 cols x 4 rows, NT: read-once), compute sw bf16 in-register.
    u16x8 rowv[RROWS];
#pragma unroll
    for (int r = 0; r < RROWS; ++r) {
        const f32x4* w4 = reinterpret_cast<const f32x4*>(
                              w + (size_t)(i0 + r) * J_DIM) + 2 * c8;
        const f32x4* m4 = reinterpret_cast<const f32x4*>(
                              m + (size_t)(i0 + r) * J_DIM) + 2 * c8;
        f32x4 w0 = __builtin_nontemporal_load(w4);
        f32x4 w1 = __builtin_nontemporal_load(w4 + 1);
        f32x4 m0 = __builtin_nontemporal_load(m4);
        f32x4 m1 = __builtin_nontemporal_load(m4 + 1);
        u16x8 o;
#pragma unroll
        for (int k = 0; k < 4; ++k) {
            o[k]     = f2bf(w0[k] * soft_mask(m0[k]));
            o[k + 4] = f2bf(w1[k] * soft_mask(m1[k]));
        }
        rowv[r] = o;
    }
    // Transpose into LDS (swizzled, conflict-free b64).
#pragma unroll
    for (int k = 0; k < 8; ++k) {
        u16x4 t;
#pragma unroll
        for (int r = 0; r < RROWS; ++r) t[r] = rowv[r][k];
        vlds[swzB(8 * c8 + k)] = t;
    }
    __syncthreads();

    // Column gather + combine.
    float o[RROWS][8];
#pragma unroll
    for (int r = 0; r < RROWS; ++r)
#pragma unroll
        for (int k = 0; k < 8; ++k) o[r][k] = 0.f;

#pragma unroll 2
    for (int q = 0; q < NPERM1; ++q) {
        const i32x4* pq = reinterpret_cast<const i32x4*>(perm1 + (size_t)q * J_DIM);
        const f32x4* sq = reinterpret_cast<const f32x4*>(ps1  + (size_t)q * J_DIM);
        i32x4 pc0 = pq[2 * c8];
        i32x4 pc1 = pq[2 * c8 + 1];
        f32x4 s0  = sq[2 * c8];
        f32x4 s1  = sq[2 * c8 + 1];
        u16x4 g[8];
#pragma unroll
        for (int k = 0; k < 4; ++k) {
            g[k]     = vlds[swzB(pc0[k])];
            g[k + 4] = vlds[swzB(pc1[k])];
        }
#pragma unroll
        for (int k = 0; k < 4; ++k) {
#pragma unroll
            for (int r = 0; r < RROWS; ++r) {
                o[r][k]     += s0[k] * bf2f(g[k][r]);
                o[r][k + 4] += s1[k] * bf2f(g[k + 4][r]);
            }
        }
    }
    // Emit u as bf16 (cached: read by K2 soon, let it live in L2/L3).
#pragma unroll
    for (int r = 0; r < RROWS; ++r) {
        u16x8 ob;
#pragma unroll
        for (int k = 0; k < 8; ++k) ob[k] = f2bf(o[r][k]);
        *reinterpret_cast<u16x8*>(ub + (size_t)(i0 + r) * J_DIM + (size_t)c8 * 8) = ob;
    }
}

// K2: row-mix on u -> final out (f32):
//   out[i,c] = sum_p ps0[p,i] * u[perm0[p,i], c]
// Column-chunked (chunk = bid % 8 -> XCD): each XCD gathers from a 4 MiB
// u slice resident in its L2. NT out stores keep that slice unevicted.
// launch_bounds(256,6): 6 blocks/CU = 24 waves (VGPR cap ~80 > the 64 this
// loop needs). (256,8) was the round-12 mistake: cap 32 -> serialized loads.
__global__ __launch_bounds__(256, 6) void rowmix_out_kernel(
    const unsigned short* __restrict__ ub,    // (I, J) bf16
    const float* __restrict__ ps0,            // (NPERM0, I)
    const int*   __restrict__ perm0,          // (NPERM0, I)
    float* __restrict__ out) {                // (I, J) f32
    const int chunk = blockIdx.x & (CHUNKS - 1);
    const int rg    = blockIdx.x / CHUNKS;
    const int wave  = threadIdx.x >> 6;
    const int lane  = threadIdx.x & 63;
    const int i0    = rg * K2_ROWS + wave * 4;           // 4 rows per wave
    const size_t colbase = (size_t)chunk * CCOLS + (size_t)lane * 8;

    float acc[4][8];
#pragma unroll
    for (int r = 0; r < 4; ++r)
#pragma unroll
        for (int k = 0; k < 8; ++k) acc[r][k] = 0.f;

#pragma unroll 2
    for (int p = 0; p < NPERM0; ++p) {
        u16x8 vv[4];
#pragma unroll
        for (int r = 0; r < 4; ++r) {
            int row = perm0[p * I_DIM + i0 + r];          // wave-uniform
            vv[r] = *reinterpret_cast<const u16x8*>(
                        ub + (size_t)row * J_DIM + colbase);
        }
#pragma unroll
        for (int r = 0; r < 4; ++r) {
            float s = ps0[p * I_DIM + i0 + r];            // wave-uniform
#pragma unroll
            for (int k = 0; k < 8; ++k) acc[r][k] += s * bf2f(vv[r][k]);
        }
    }
#pragma unroll
    for (int r = 0; r < 4; ++r) {
        f32x4 t0, t1;
#pragma unroll
        for (int k = 0; k < 4; ++k) { t0[k] = acc[r][k]; t1[k] = acc[r][k + 4]; }
        float* dst = out + (size_t)(i0 + r) * J_DIM + colbase;
        __builtin_nontemporal_store(t0, reinterpret_cast<f32x4*>(dst));
        __builtin_nontemporal_store(t1, reinterpret_cast<f32x4*>(dst) + 1);
    }
}

extern "C" void kernel_launch(void* const* d_in, const int* in_sizes, int n_in,
                              void* d_out, int out_size, void* d_ws, size_t ws_size,
                              hipStream_t stream) {
    const float* weight = (const float*)d_in[0];
    const float* smask  = (const float*)d_in[1];
    const float* ps0    = (const float*)d_in[2];
    const float* ps1    = (const float*)d_in[3];
    const int*   perm0  = (const int*)d_in[4];
    const int*   perm1  = (const int*)d_in[5];
    float* out = (float*)d_out;

    unsigned short* ub = (unsigned short*)d_ws;   // 32 MiB intermediate u

    maskcolmix_kernel<<<I_DIM / RROWS, 512, 0, stream>>>(
        weight, smask, ps1, perm1, ub);
    rowmix_out_kernel<<<CHUNKS * (I_DIM / K2_ROWS), 256, 0, stream>>>(
        ub, ps0, perm0, out);
}

// Round 14
// 68.662 us; speedup vs baseline: 1.5087x; 1.3450x over previous
//
#include <hip/hip_runtime.h>
#include <hip/hip_bf16.h>

#define I_DIM 4096
#define J_DIM 4096
#define NPERM0 10
#define NPERM1 10
#define RROWS 4            // rows per K1 block
#define CHUNKS 8           // column chunks == XCD count
#define CCOLS (J_DIM / CHUNKS)   // 512 cols per chunk (4 MiB bf16 slice)
#define K2_ROWS 16         // out rows per K2 block (4 waves x 4 rows)

typedef float          f32x4 __attribute__((ext_vector_type(4)));
typedef int            i32x4 __attribute__((ext_vector_type(4)));
typedef unsigned short u16x4 __attribute__((ext_vector_type(4)));
typedef unsigned short u16x8 __attribute__((ext_vector_type(8)));

// XOR-swizzle for 8-byte LDS slots: physical = s ^ ((s>>4)&7). Bijective.
// Transpose writes (s = 8*c8+k, fixed k): 16 consecutive lanes hit 16
// distinct low-4 slots -> all 32 banks exactly 4x per wave (b64 optimum).
__device__ __forceinline__ int swzB(int s) { return s ^ ((s >> 4) & 7); }

__device__ __forceinline__ float bf2f(unsigned short u) {
    return __uint_as_float((unsigned)u << 16);
}
__device__ __forceinline__ unsigned short f2bf(float f) {
    unsigned u = __float_as_uint(f);
    u += 0x7FFFu + ((u >> 16) & 1u);
    return (unsigned short)(u >> 16);
}

// soft mask: clip((xi-gamma)*sigmoid(x)+gamma, 0, 1), xi=1.1, gamma=-0.1
__device__ __forceinline__ float soft_mask(float x) {
    float s = 1.0f / (1.0f + __expf(-x));
    return fminf(fmaxf(1.2f * s - 0.1f, 0.0f), 1.0f);
}

// K1: fused soft-mask + column-mix (round-11 proven body, 50 us @ VGPR 40):
//   u[i,c] = sum_q ps1[q,c] * sw[i, perm1[q,c]],  sw[i,j] = w[i,j]*mask(m[i,j])
// launch_bounds(512,4): VGPR cap 128. Lower caps ((512,8)->32 VGPR,
// (256,8)->32) spilled or serialized in rounds 7/12/13 — never cap below
// ~96 for this body.
// ROUND-14 CHANGE: w/m loads are REGULAR (cached), not non-temporal.
// w+m (128 MB) + ub (32) + out (64) = 224 MB < 256 MB L3: with cached
// loads they stay L3-resident across graph replays; NT hinted no-allocate
// and forced partial HBM re-fetch every replay (round-11 FETCH=75 MB).
__global__ __launch_bounds__(512, 4) void maskcolmix_kernel(
    const float* __restrict__ w,              // (I, J) f32
    const float* __restrict__ m,              // (I, J) f32
    const float* __restrict__ ps1,            // (NPERM1, J)
    const int*   __restrict__ perm1,          // (NPERM1, J)
    unsigned short* __restrict__ ub) {        // (I, J) bf16 out
    __shared__ u16x4 vlds[J_DIM];             // 32 KiB

    const int i0 = blockIdx.x * RROWS;
    const int c8 = threadIdx.x;               // column octet, 0..511

    // Load w,m (8 cols x 4 rows, cached), compute sw bf16 in-register.
    u16x8 rowv[RROWS];
#pragma unroll
    for (int r = 0; r < RROWS; ++r) {
        const f32x4* w4 = reinterpret_cast<const f32x4*>(
                              w + (size_t)(i0 + r) * J_DIM) + 2 * c8;
        const f32x4* m4 = reinterpret_cast<const f32x4*>(
                              m + (size_t)(i0 + r) * J_DIM) + 2 * c8;
        f32x4 w0 = w4[0];
        f32x4 w1 = w4[1];
        f32x4 m0 = m4[0];
        f32x4 m1 = m4[1];
        u16x8 o;
#pragma unroll
        for (int k = 0; k < 4; ++k) {
            o[k]     = f2bf(w0[k] * soft_mask(m0[k]));
            o[k + 4] = f2bf(w1[k] * soft_mask(m1[k]));
        }
        rowv[r] = o;
    }
    // Transpose into LDS (swizzled, conflict-free b64).
#pragma unroll
    for (int k = 0; k < 8; ++k) {
        u16x4 t;
#pragma unroll
        for (int r = 0; r < RROWS; ++r) t[r] = rowv[r][k];
        vlds[swzB(8 * c8 + k)] = t;
    }
    __syncthreads();

    // Column gather + combine.
    float o[RROWS][8];
#pragma unroll
    for (int r = 0; r < RROWS; ++r)
#pragma unroll
        for (int k = 0; k < 8; ++k) o[r][k] = 0.f;

#pragma unroll 2
    for (int q = 0; q < NPERM1; ++q) {
        const i32x4* pq = reinterpret_cast<const i32x4*>(perm1 + (size_t)q * J_DIM);
        const f32x4* sq = reinterpret_cast<const f32x4*>(ps1  + (size_t)q * J_DIM);
        i32x4 pc0 = pq[2 * c8];
        i32x4 pc1 = pq[2 * c8 + 1];
        f32x4 s0  = sq[2 * c8];
        f32x4 s1  = sq[2 * c8 + 1];
        u16x4 g[8];
#pragma unroll
        for (int k = 0; k < 4; ++k) {
            g[k]     = vlds[swzB(pc0[k])];
            g[k + 4] = vlds[swzB(pc1[k])];
        }
#pragma unroll
        for (int k = 0; k < 4; ++k) {
#pragma unroll
            for (int r = 0; r < RROWS; ++r) {
                o[r][k]     += s0[k] * bf2f(g[k][r]);
                o[r][k + 4] += s1[k] * bf2f(g[k + 4][r]);
            }
        }
    }
    // Emit u as bf16 (cached: read by K2 soon, let it live in L2/L3).
#pragma unroll
    for (int r = 0; r < RROWS; ++r) {
        u16x8 ob;
#pragma unroll
        for (int k = 0; k < 8; ++k) ob[k] = f2bf(o[r][k]);
        *reinterpret_cast<u16x8*>(ub + (size_t)(i0 + r) * J_DIM + (size_t)c8 * 8) = ob;
    }
}

// K2: row-mix on u -> final out (f32):
//   out[i,c] = sum_p ps0[p,i] * u[perm0[p,i], c]
// Column-chunked (chunk = bid % 8 -> XCD): each XCD gathers from a 4 MiB
// u slice resident in its L2. NT out stores keep that slice unevicted
// (out is write-once; keeping it out of L2/L3 protects ub residency).
// launch_bounds(256,4): VGPR cap 128; this body needs 64 (round-6 proven).
__global__ __launch_bounds__(256, 4) void rowmix_out_kernel(
    const unsigned short* __restrict__ ub,    // (I, J) bf16
    const float* __restrict__ ps0,            // (NPERM0, I)
    const int*   __restrict__ perm0,          // (NPERM0, I)
    float* __restrict__ out) {                // (I, J) f32
    const int chunk = blockIdx.x & (CHUNKS - 1);
    const int rg    = blockIdx.x / CHUNKS;
    const int wave  = threadIdx.x >> 6;
    const int lane  = threadIdx.x & 63;
    const int i0    = rg * K2_ROWS + wave * 4;           // 4 rows per wave
    const size_t colbase = (size_t)chunk * CCOLS + (size_t)lane * 8;

    float acc[4][8];
#pragma unroll
    for (int r = 0; r < 4; ++r)
#pragma unroll
        for (int k = 0; k < 8; ++k) acc[r][k] = 0.f;

#pragma unroll 2
    for (int p = 0; p < NPERM0; ++p) {
        u16x8 vv[4];
#pragma unroll
        for (int r = 0; r < 4; ++r) {
            int row = perm0[p * I_DIM + i0 + r];          // wave-uniform
            vv[r] = *reinterpret_cast<const u16x8*>(
                        ub + (size_t)row * J_DIM + colbase);
        }
#pragma unroll
        for (int r = 0; r < 4; ++r) {
            float s = ps0[p * I_DIM + i0 + r];            // wave-uniform
#pragma unroll
            for (int k = 0; k < 8; ++k) acc[r][k] += s * bf2f(vv[r][k]);
        }
    }
#pragma unroll
    for (int r = 0; r < 4; ++r) {
        f32x4 t0, t1;
#pragma unroll
        for (int k = 0; k < 4; ++k) { t0[k] = acc[r][k]; t1[k] = acc[r][k + 4]; }
        float* dst = out + (size_t)(i0 + r) * J_DIM + colbase;
        __builtin_nontemporal_store(t0, reinterpret_cast<f32x4*>(dst));
        __builtin_nontemporal_store(t1, reinterpret_cast<f32x4*>(dst) + 1);
    }
}

extern "C" void kernel_launch(void* const* d_in, const int* in_sizes, int n_in,
                              void* d_out, int out_size, void* d_ws, size_t ws_size,
                              hipStream_t stream) {
    const float* weight = (const float*)d_in[0];
    const float* smask  = (const float*)d_in[1];
    const float* ps0    = (const float*)d_in[2];
    const float* ps1    = (const float*)d_in[3];
    const int*   perm0  = (const int*)d_in[4];
    const int*   perm1  = (const int*)d_in[5];
    float* out = (float*)d_out;

    unsigned short* ub = (unsigned short*)d_ws;   // 32 MiB intermediate u

    maskcolmix_kernel<<<I_DIM / RROWS, 512, 0, stream>>>(
        weight, smask, ps1, perm1, ub);
    rowmix_out_kernel<<<CHUNKS * (I_DIM / K2_ROWS), 256, 0, stream>>>(
        ub, ps0, perm0, out);
}